// Round 4
// baseline (85.789 us; speedup 1.0000x reference)
//
#include <hip/hip_runtime.h>

// CumulativeFlattenedLinear: per-64-timestep-window projection (C=16 -> O=16,
// per-s weight slice, first ND=16 slots zero) + causal cumsum in window + bias.
//
// v4: lane = s (window == wave task). KEY CHANGE vs v3: o-chunk shrunk 8 -> 4
// so the register weight slice wreg[4][16] is only 64 VGPRs -- small enough
// that the allocator actually keeps it resident (v3's wreg[8][16]=128 regs
// was spilled/sunk: VGPR_Count=84 proved it, and the kernel became a
// latency-bound reload loop). Total pressure ~110 under launch_bounds(256,4)
// -> 4 waves/SIMD, 16 waves/CU (~50% occupancy, 2.7x v3).
//
// Task layout: block b handles 4 consecutive windows; its 4 waves are the 4
// o-chunks over those same windows (x re-reads hit L1/L2). Window loop fully
// unrolled -> next window's 16 x-loads overlap current window's scan/stores.
// Per window-task: 16 coalesced x loads, 64 FMA, 4 DPP scans, 4 coalesced
// stores. No LDS, no barriers.

#define CC 16
#define TT 131072
#define OO 16
#define NK 48
#define ND 16
#define GG 2048          // windows per batch row
#define OCH 4            // outputs per wave
#define WPW 4            // windows per wave

// 64-lane inclusive prefix sum via DPP (verified R1).
#define SCAN_STEP(CTRL, RMASK)                                                  \
  {                                                                             \
    int t_ = __builtin_amdgcn_update_dpp(0, __float_as_int(v), (CTRL), (RMASK), \
                                         0xf, true);                            \
    v += __int_as_float(t_);                                                    \
  }

__device__ __forceinline__ float wave_scan64(float v) {
  SCAN_STEP(0x111, 0xf)  // row_shr:1
  SCAN_STEP(0x112, 0xf)  // row_shr:2
  SCAN_STEP(0x114, 0xf)  // row_shr:4
  SCAN_STEP(0x118, 0xf)  // row_shr:8
  SCAN_STEP(0x142, 0xa)  // row_bcast15
  SCAN_STEP(0x143, 0xc)  // row_bcast31
  return v;
}

__global__ __launch_bounds__(256, 4) void cfl_kernel(
    const float* __restrict__ x, const float* __restrict__ weight,
    const float* __restrict__ bias, float* __restrict__ out) {
  const int tid = threadIdx.x;
  const int lane = tid & 63;
  const int wid = tid >> 6;          // o-chunk id (0..3)

  const int o0 = wid * OCH;
  const int n0 = blockIdx.x * WPW;   // first window of this block

  // Register-resident per-lane weight slice: wreg[oo][c] = w[o0+oo][c][lane]
  // (zero for discard slots lane<ND). 64 VGPRs. Pinned against sinking.
  float wreg[OCH][CC];
#pragma unroll
  for (int oo = 0; oo < OCH; ++oo) {
#pragma unroll
    for (int c = 0; c < CC; ++c) {
      float wv = 0.f;
      if (lane >= ND) wv = weight[(o0 + oo) * (CC * NK) + c * NK + (lane - ND)];
      asm volatile("" : "+v"(wv));
      wreg[oo][c] = wv;
    }
  }

  float bo[OCH];
#pragma unroll
  for (int oo = 0; oo < OCH; ++oo) bo[oo] = bias[o0 + oo];

#pragma unroll
  for (int k = 0; k < WPW; ++k) {
    const int n = n0 + k;
    const int b = n >> 11;           // / GG
    const int g = n & (GG - 1);

    const float* xb = x + (size_t)b * CC * TT + g * 64 + lane;
    float xv[CC];
#pragma unroll
    for (int c = 0; c < CC; ++c) xv[c] = xb[(size_t)c * TT];

    float p[OCH];
#pragma unroll
    for (int oo = 0; oo < OCH; ++oo) p[oo] = 0.f;
#pragma unroll
    for (int c = 0; c < CC; ++c)
#pragma unroll
      for (int oo = 0; oo < OCH; ++oo)
        p[oo] = fmaf(xv[c], wreg[oo][c], p[oo]);

    float* ob = out + (size_t)b * OO * TT + g * 64 + lane;
#pragma unroll
    for (int oo = 0; oo < OCH; ++oo) {
      float cs = wave_scan64(p[oo]);
      ob[(size_t)(o0 + oo) * TT] = cs + bo[oo];
    }
  }
}

extern "C" void kernel_launch(void* const* d_in, const int* in_sizes, int n_in,
                              void* d_out, int out_size, void* d_ws, size_t ws_size,
                              hipStream_t stream) {
  const float* x = (const float*)d_in[0];
  const float* weight = (const float*)d_in[1];
  const float* bias = (const float*)d_in[2];
  float* out = (float*)d_out;

  // 16384 windows / 4 per block -> 4096 blocks; 4 waves = 4 o-chunks.
  cfl_kernel<<<4096, 256, 0, stream>>>(x, weight, bias, out);
}

// Round 5
// 31.227 us; speedup vs baseline: 2.7472x; 2.7472x over previous
//
#include <hip/hip_runtime.h>

// CumulativeFlattenedLinear: per-64-timestep-window projection (C=16 -> O=16,
// per-s weight slice, first ND=16 slots zero) + causal cumsum in window + bias.
//
// v5: lane = s. The R2/R3/R4 lesson: the allocator spills/sinks any long-lived
// per-lane array > ~32 floats (R3's scratch traffic, R4's VGPR=64), so the o-
// amplified operand must come from LDS, not registers or L1.
//   - Block stages a 4-window x-tile (256 t x 16 c fp32, 16 KiB) into LDS in
//     granule-major layout [c4][t][4c]: ds_read_b128 gives each lane 4
//     consecutive c, statically indexed, bank = t%8 -> conflict-free reads.
//     Staging writes are 4-way aliased (1.58x, negligible volume).
//   - Each wave handles an o-PAIR per phase (w0[16]+w1[16] = 32 regs, the
//     R1-proven safe residency scale), 2 phases x 4 windows. LDS re-read
//     volume = 8 reads of x per element = 0.5 GB ~= 7 us of LDS pipe, hidden
//     under the ~20 us HBM floor (64 MiB in + 64 MiB out).
//   - 16 KiB LDS, single-buffered, 8 blocks/CU (thread-capped) -> TLP hides
//     stage->compute serialization.

#define CC 16
#define TT 131072
#define OO 16
#define NK 48
#define ND 16
#define WPB 4            // windows per block tile
#define GG 2048          // windows per batch row

// 64-lane inclusive prefix sum via DPP (verified R1).
#define SCAN_STEP(CTRL, RMASK)                                                  \
  {                                                                             \
    int t_ = __builtin_amdgcn_update_dpp(0, __float_as_int(v), (CTRL), (RMASK), \
                                         0xf, true);                            \
    v += __int_as_float(t_);                                                    \
  }

__device__ __forceinline__ float wave_scan64(float v) {
  SCAN_STEP(0x111, 0xf)  // row_shr:1
  SCAN_STEP(0x112, 0xf)  // row_shr:2
  SCAN_STEP(0x114, 0xf)  // row_shr:4
  SCAN_STEP(0x118, 0xf)  // row_shr:8
  SCAN_STEP(0x142, 0xa)  // row_bcast15
  SCAN_STEP(0x143, 0xc)  // row_bcast31
  return v;
}

__global__ __launch_bounds__(256, 4) void cfl_kernel(
    const float* __restrict__ x, const float* __restrict__ weight,
    const float* __restrict__ bias, float* __restrict__ out) {
  // granule-major tile: [c4:4][t:256][4 floats] = 16 KiB
  __shared__ float tile[4 * 256 * 4];

  const int tid = threadIdx.x;
  const int lane = tid & 63;
  const int wid = tid >> 6;

  const int n0 = blockIdx.x * WPB;      // first window (b*GG + g)
  const int b = n0 >> 11;               // / GG
  const int t0 = (n0 & (GG - 1)) * 64;  // t offset within the batch row

  // ---- stage x tile (fully coalesced dword loads; 4-way-aliased b32 writes)
  const float* xb = x + (size_t)b * CC * TT + t0;
#pragma unroll
  for (int c = 0; c < CC; ++c) {
    float v = xb[(size_t)c * TT + tid];
    tile[(((c >> 2) * 256 + tid) << 2) + (c & 3)] = v;
  }
  __syncthreads();

  float* ob = out + (size_t)b * OO * TT + t0;

#pragma unroll
  for (int p = 0; p < 2; ++p) {
    const int o0 = p * 4 + wid;  // this wave's o-pair: (o0, o0+8)

    // o-pair weight slices: 32 long-lived regs (safe scale per R1).
    float w0[CC], w1[CC];
#pragma unroll
    for (int c = 0; c < CC; ++c) {
      w0[c] = (lane >= ND) ? weight[o0 * (CC * NK) + c * NK + (lane - ND)] : 0.f;
      w1[c] = (lane >= ND) ? weight[(o0 + 8) * (CC * NK) + c * NK + (lane - ND)] : 0.f;
    }
    const float b0 = bias[o0];
    const float b1 = bias[o0 + 8];

#pragma unroll
    for (int k = 0; k < WPB; ++k) {
      const int t = k * 64 + lane;
      // 4x ds_read_b128, statically indexed, conflict-free (bank = t%8)
      float4 xq0 = *(const float4*)&tile[(0 * 256 + t) << 2];
      float4 xq1 = *(const float4*)&tile[(1 * 256 + t) << 2];
      float4 xq2 = *(const float4*)&tile[(2 * 256 + t) << 2];
      float4 xq3 = *(const float4*)&tile[(3 * 256 + t) << 2];

      float p0 = 0.f, p1 = 0.f;
      p0 = fmaf(xq0.x, w0[0], p0);  p1 = fmaf(xq0.x, w1[0], p1);
      p0 = fmaf(xq0.y, w0[1], p0);  p1 = fmaf(xq0.y, w1[1], p1);
      p0 = fmaf(xq0.z, w0[2], p0);  p1 = fmaf(xq0.z, w1[2], p1);
      p0 = fmaf(xq0.w, w0[3], p0);  p1 = fmaf(xq0.w, w1[3], p1);
      p0 = fmaf(xq1.x, w0[4], p0);  p1 = fmaf(xq1.x, w1[4], p1);
      p0 = fmaf(xq1.y, w0[5], p0);  p1 = fmaf(xq1.y, w1[5], p1);
      p0 = fmaf(xq1.z, w0[6], p0);  p1 = fmaf(xq1.z, w1[6], p1);
      p0 = fmaf(xq1.w, w0[7], p0);  p1 = fmaf(xq1.w, w1[7], p1);
      p0 = fmaf(xq2.x, w0[8], p0);  p1 = fmaf(xq2.x, w1[8], p1);
      p0 = fmaf(xq2.y, w0[9], p0);  p1 = fmaf(xq2.y, w1[9], p1);
      p0 = fmaf(xq2.z, w0[10], p0); p1 = fmaf(xq2.z, w1[10], p1);
      p0 = fmaf(xq2.w, w0[11], p0); p1 = fmaf(xq2.w, w1[11], p1);
      p0 = fmaf(xq3.x, w0[12], p0); p1 = fmaf(xq3.x, w1[12], p1);
      p0 = fmaf(xq3.y, w0[13], p0); p1 = fmaf(xq3.y, w1[13], p1);
      p0 = fmaf(xq3.z, w0[14], p0); p1 = fmaf(xq3.z, w1[14], p1);
      p0 = fmaf(xq3.w, w0[15], p0); p1 = fmaf(xq3.w, w1[15], p1);

      const float cs0 = wave_scan64(p0);
      const float cs1 = wave_scan64(p1);
      ob[(size_t)o0 * TT + t] = cs0 + b0;
      ob[(size_t)(o0 + 8) * TT + t] = cs1 + b1;
    }
  }
}

extern "C" void kernel_launch(void* const* d_in, const int* in_sizes, int n_in,
                              void* d_out, int out_size, void* d_ws, size_t ws_size,
                              hipStream_t stream) {
  const float* x = (const float*)d_in[0];
  const float* weight = (const float*)d_in[1];
  const float* bias = (const float*)d_in[2];
  float* out = (float*)d_out;

  // 16384 windows / 4 per block = 4096 blocks.
  cfl_kernel<<<4096, 256, 0, stream>>>(x, weight, bias, out);
}